// Round 1
// baseline (3392.188 us; speedup 1.0000x reference)
//
#include <hip/hip_runtime.h>

#define NW_MAX 100000
#define ML 24
#define EMBD 50
#define HID 50
#define BLK 256

__device__ __forceinline__ float sigm(float x) {
    return __fdividef(1.0f, 1.0f + __expf(-x));
}
__device__ __forceinline__ float tanhfast(float x) {
    float e = __expf(2.0f * x);
    return __fdividef(e - 1.0f, e + 1.0f);
}

// ---------- length bucket sort (output-deterministic; perm order within a
// bucket is atomic-order-dependent, but each word writes only its own row) ---
// ws layout (ints): [0,25) counts, [25,50) bases, [50,75) cursors, [100,100+NW) perm
__global__ void zero_counts_kernel(int* ws) {
    if (threadIdx.x < 75) ws[threadIdx.x] = 0;
}
__global__ void hist_kernel(const int* __restrict__ lengths, int* ws, int nw) {
    int i = blockIdx.x * blockDim.x + threadIdx.x;
    if (i < nw) atomicAdd(&ws[lengths[i]], 1);
}
__global__ void prefix_kernel(int* ws) {
    if (threadIdx.x == 0 && blockIdx.x == 0) {
        int acc = 0;
        for (int l = 0; l <= ML; ++l) { ws[25 + l] = acc; acc += ws[l]; }
    }
}
__global__ void scatter_kernel(const int* __restrict__ lengths, int* ws, int nw) {
    int i = blockIdx.x * blockDim.x + threadIdx.x;
    if (i < nw) {
        int l = lengths[i];
        int pos = ws[25 + l] + atomicAdd(&ws[50 + l], 1);
        ws[100 + pos] = i;
    }
}

// ---------- main: one lane = one (word, direction) ----------
__global__ __launch_bounds__(BLK, 2)
void bilstm_kernel(const int* __restrict__ chars,
                   const int* __restrict__ lengths,
                   const float* __restrict__ emb,
                   const float* __restrict__ Wih_f, const float* __restrict__ Whh_f, const float* __restrict__ b_f,
                   const float* __restrict__ Wih_b, const float* __restrict__ Whh_b, const float* __restrict__ b_b,
                   const int* __restrict__ perm,
                   float* __restrict__ out, int nw)
{
    const int dir = blockIdx.y;
    const float* Wih = dir ? Wih_b : Wih_f;
    const float* Whh = dir ? Whh_b : Whh_f;
    const float* bv  = dir ? b_b  : b_f;

    // sWU4[j*100 + k] = {W[j][k], W[j+50][k], W[j+100][k], W[j+150][k]}
    // where k<50 -> Wih col k, k>=50 -> Whh col k-50.  80 KB -> 2 blocks/CU.
    __shared__ float4 sWU4[HID * 100];
    __shared__ float4 sB4[HID];

    {
        float* p = (float*)sWU4;
        for (int i = threadIdx.x; i < HID * 100 * 4; i += BLK) {
            int g = i & 3;
            int r = i >> 2;
            int j = r / 100;
            int k = r - j * 100;
            p[i] = (k < EMBD) ? Wih[(j + g * HID) * EMBD + k]
                              : Whh[(j + g * HID) * HID + (k - EMBD)];
        }
        if (threadIdx.x < HID) {
            int j = threadIdx.x;
            sB4[j] = make_float4(bv[j], bv[j + HID], bv[j + 2*HID], bv[j + 3*HID]);
        }
    }
    __syncthreads();

    int gid = blockIdx.x * BLK + threadIdx.x;
    if (gid >= nw) return;
    int word = perm ? perm[gid] : gid;
    int len  = lengths[word];

    float h[HID], x[EMBD];   // register arrays (static-indexed only)
    float c[HID], hn[HID];   // dynamic-indexed -> scratch (accepted)
#pragma unroll
    for (int j = 0; j < HID; ++j) h[j] = 0.f;
#pragma unroll 1
    for (int j = 0; j < HID; ++j) c[j] = 0.f;

    const int* wch = chars + word * ML;
    float* op = out + (size_t)word * (2 * HID) + dir * HID;

#pragma unroll 1
    for (int t = 0; t < len; ++t) {
        int pos = dir ? (len - 1 - t) : t;
        int ch = wch[pos];
        const float2* ep = (const float2*)(emb + ch * EMBD);
#pragma unroll
        for (int k = 0; k < EMBD / 2; ++k) {
            float2 v = ep[k];
            x[2*k] = v.x; x[2*k + 1] = v.y;
        }
#pragma unroll 1
        for (int j = 0; j < HID; ++j) {
            const float4* wp = sWU4 + j * 100;   // wave-uniform -> LDS broadcast
            float4 bb = sB4[j];
            float gi = bb.x, gf = bb.y, gg = bb.z, go = bb.w;
#pragma unroll
            for (int k = 0; k < EMBD; ++k) {
                float4 w = wp[k];
                float xv = x[k];
                gi += w.x * xv; gf += w.y * xv; gg += w.z * xv; go += w.w * xv;
            }
#pragma unroll
            for (int k = 0; k < HID; ++k) {
                float4 w = wp[EMBD + k];
                float hv = h[k];
                gi += w.x * hv; gf += w.y * hv; gg += w.z * hv; go += w.w * hv;
            }
            float cn = sigm(gf) * c[j] + sigm(gi) * tanhfast(gg);
            c[j] = cn;
            hn[j] = sigm(go) * tanhfast(cn);
        }
#pragma unroll
        for (int j = 0; j < HID; ++j) h[j] = hn[j];
    }

#pragma unroll
    for (int j = 0; j < HID / 2; ++j)
        ((float2*)op)[j] = make_float2(h[2*j], h[2*j + 1]);
}

extern "C" void kernel_launch(void* const* d_in, const int* in_sizes, int n_in,
                              void* d_out, int out_size, void* d_ws, size_t ws_size,
                              hipStream_t stream) {
    const int*   chars = (const int*)  d_in[0];
    const int*   lens  = (const int*)  d_in[1];
    const float* emb   = (const float*)d_in[2];
    const float* Wih_f = (const float*)d_in[3];
    const float* Whh_f = (const float*)d_in[4];
    const float* b_f   = (const float*)d_in[5];
    const float* Wih_b = (const float*)d_in[6];
    const float* Whh_b = (const float*)d_in[7];
    const float* b_b   = (const float*)d_in[8];
    float* out = (float*)d_out;

    const int nw = in_sizes[1];   // lengths count = word count

    int* ws = (int*)d_ws;
    const int* perm = nullptr;
    if (ws_size >= (size_t)(100 + nw) * sizeof(int)) {
        zero_counts_kernel<<<1, 128, 0, stream>>>(ws);
        hist_kernel<<<(nw + 255) / 256, 256, 0, stream>>>(lens, ws, nw);
        prefix_kernel<<<1, 1, 0, stream>>>(ws);
        scatter_kernel<<<(nw + 255) / 256, 256, 0, stream>>>(lens, ws, nw);
        perm = ws + 100;
    }

    dim3 grid((nw + BLK - 1) / BLK, 2);
    bilstm_kernel<<<grid, BLK, 0, stream>>>(chars, lens, emb,
                                            Wih_f, Whh_f, b_f,
                                            Wih_b, Whh_b, b_b,
                                            perm, out, nw);
}

// Round 6
// 1754.498 us; speedup vs baseline: 1.9334x; 1.9334x over previous
//
#include <hip/hip_runtime.h>

#define EMBD 50
#define HID 50
#define BLK 256

typedef float f32x4 __attribute__((ext_vector_type(4)));
typedef short short8 __attribute__((ext_vector_type(8)));

__device__ __forceinline__ int imax(int a, int b) { return a > b ? a : b; }
__device__ __forceinline__ int imin(int a, int b) { return a < b ? a : b; }

__device__ __forceinline__ unsigned short f2bf(float f) {
    unsigned u = __float_as_uint(f);
    u += 0x7FFFu + ((u >> 16) & 1u);
    return (unsigned short)(u >> 16);
}
__device__ __forceinline__ float sigm(float x) {
    return __fdividef(1.0f, 1.0f + __expf(-x));
}
__device__ __forceinline__ float tanhfast(float x) {
    float e = __expf(2.0f * x);
    return 1.0f - __fdividef(2.0f, e + 1.0f);
}

// ---------------- length bucket sort (as R1) ----------------
// ws ints: [0,25) counts, [25,50) bases, [50,75) cursors, [100,100+NW) perm
__global__ void zero_counts_kernel(int* ws) {
    if (threadIdx.x < 75) ws[threadIdx.x] = 0;
}
__global__ void hist_kernel(const int* __restrict__ lengths, int* ws, int nw) {
    int i = blockIdx.x * blockDim.x + threadIdx.x;
    if (i < nw) atomicAdd(&ws[lengths[i]], 1);
}
__global__ void prefix_kernel(int* ws) {
    if (threadIdx.x == 0 && blockIdx.x == 0) {
        int acc = 0;
        for (int l = 0; l <= 24; ++l) { ws[25 + l] = acc; acc += ws[l]; }
    }
}
__global__ void scatter_kernel(const int* __restrict__ lengths, int* ws, int nw) {
    int i = blockIdx.x * blockDim.x + threadIdx.x;
    if (i < nw) {
        int l = lengths[i];
        int pos = ws[25 + l] + atomicAdd(&ws[50 + l], 1);
        ws[100 + pos] = i;
    }
}

// ---------------- packing kernels ----------------
// emb_pad[v][e]: e<50 -> emb, e==63 -> 1.0 (bias lane), else 0.   [vocab][64] bf16
__global__ void pack_emb_kernel(const float* __restrict__ emb, unsigned short* __restrict__ embp,
                                int vocab) {
    int i = blockIdx.x * blockDim.x + threadIdx.x;
    if (i >= vocab * 64) return;
    int v = i >> 6, e = i & 63;
    float val = (e < EMBD) ? emb[v * EMBD + e] : (e == 63 ? 1.0f : 0.0f);
    embp[i] = f2bf(val);
}

// Weight A-fragments, row-permuted so feedback is lane-local.
// Padded gate row P = gt*16 + m (m = lane&15).  b = P>>6 gate block (i/f/g/o),
// pp = P&63: tt=pp>>4, ss=(pp>>2)&3, qq=pp&3 -> hidden j = 32*(qq>>1)+8*ss+2*tt+(qq&1).
// k-slot: kk = kc*32 + 8*(lane>>4) + i.  kk<64: x-part (e=kk; e==63 -> bias), else h-part.
__global__ void pack_w_kernel(const float* __restrict__ Wih_f, const float* __restrict__ Whh_f,
                              const float* __restrict__ b_f,
                              const float* __restrict__ Wih_b, const float* __restrict__ Whh_b,
                              const float* __restrict__ b_b,
                              unsigned short* __restrict__ wp) {
    int tid = blockIdx.x * blockDim.x + threadIdx.x;
    if (tid >= 65536) return;
    int i    = tid & 7;
    int lane = (tid >> 3) & 63;
    int kc   = (tid >> 9) & 3;
    int gt   = (tid >> 11) & 15;
    int dir  = (tid >> 15) & 1;
    const float* Wih = dir ? Wih_b : Wih_f;
    const float* Whh = dir ? Whh_b : Whh_f;
    const float* bv  = dir ? b_b   : b_f;

    int m = lane & 15, grp = lane >> 4;
    int P = gt * 16 + m;
    int b = P >> 6, pp = P & 63;
    int tt = pp >> 4, ss = (pp >> 2) & 3, qq = pp & 3;
    int j = 32 * (qq >> 1) + 8 * ss + 2 * tt + (qq & 1);
    int kk = kc * 32 + 8 * grp + i;

    float val = 0.0f;
    if (j < HID) {
        int row = b * HID + j;
        if (kk < 64) {
            if (kk < EMBD)      val = Wih[row * EMBD + kk];
            else if (kk == 63)  val = bv[row];
        } else {
            int hk = kk - 64;
            if (hk < HID)       val = Whh[row * HID + hk];
        }
    }
    wp[tid] = f2bf(val);
}

// ---------------- main MFMA kernel ----------------
template<int KC>
__device__ __forceinline__ void mfma_kc(const unsigned short* __restrict__ sWl,
                                        short8 bb, f32x4* acc) {
#pragma unroll
    for (int gt = 0; gt < 16; ++gt) {
        const short8 aw = *(const short8*)(sWl + (gt * 4 + KC) * 512);
        acc[gt] = __builtin_amdgcn_mfma_f32_16x16x32_bf16(aw, bb, acc[gt], 0, 0, 0);
    }
}

__global__ __launch_bounds__(BLK, 2)
void bilstm_mfma_kernel(const int* __restrict__ chars,
                        const int* __restrict__ lengths,
                        const int* __restrict__ perm,
                        const unsigned short* __restrict__ embp,
                        const unsigned short* __restrict__ wp,
                        float* __restrict__ out, int nw, int ml)
{
    const int dir = blockIdx.y;
    __shared__ unsigned short sW[32768];   // 64 KB of A-fragments for this dir
    {
        const float4* src = (const float4*)(wp + dir * 32768);
        float4* dst = (float4*)sW;
        for (int i = threadIdx.x; i < 4096; i += BLK) dst[i] = src[i];
    }
    __syncthreads();

    const int lane = threadIdx.x & 63;
    const int wv   = threadIdx.x >> 6;
    const int wcol = lane & 15;          // word column
    const int s    = lane >> 4;          // lane group

    int gidx = (blockIdx.x * 4 + wv) * 16 + wcol;
    gidx = imin(gidx, nw - 1);
    const int word = perm[gidx];
    const int len  = lengths[word];

    int lmax = len;
    lmax = imax(lmax, __shfl_xor(lmax, 1));
    lmax = imax(lmax, __shfl_xor(lmax, 2));
    lmax = imax(lmax, __shfl_xor(lmax, 4));
    lmax = imax(lmax, __shfl_xor(lmax, 8));

    const int* charp = chars + (size_t)word * ml;
    const unsigned short* sWl = sW + lane * 8;

    float cst[4][4], ho[4][4];
#pragma unroll
    for (int a = 0; a < 4; ++a)
#pragma unroll
        for (int b = 0; b < 4; ++b) { cst[a][b] = 0.0f; ho[a][b] = 0.0f; }
    short8 bh0, bh1;
#pragma unroll
    for (int i2 = 0; i2 < 8; ++i2) { bh0[i2] = 0; bh1[i2] = 0; }

    // prefetch x for t=0
    short8 cx0, cx1;
    if (lmax > 0) {
        int pos0 = dir ? imax(len - 1, 0) : 0;
        int ch = charp[pos0];
        cx0 = *(const short8*)(embp + ch * 64 + 8 * s);
        cx1 = *(const short8*)(embp + ch * 64 + 32 + 8 * s);
    }

    for (int t = 0; t < lmax; ++t) {
        f32x4 acc[16];
        const f32x4 zz = {0.0f, 0.0f, 0.0f, 0.0f};
#pragma unroll
        for (int gt = 0; gt < 16; ++gt) acc[gt] = zz;

        mfma_kc<0>(sWl, cx0, acc);
        mfma_kc<1>(sWl, cx1, acc);
        mfma_kc<2>(sWl, bh0, acc);
        mfma_kc<3>(sWl, bh1, acc);

        // prefetch next step's x while MFMAs retire
        int tn = (t + 1 < lmax) ? t + 1 : t;
        int posn = dir ? imax(len - 1 - tn, 0) : tn;
        int chn = charp[posn];
        short8 nx0 = *(const short8*)(embp + chn * 64 + 8 * s);
        short8 nx1 = *(const short8*)(embp + chn * 64 + 32 + 8 * s);

        const bool upd = (t < len);
#pragma unroll
        for (int tt = 0; tt < 4; ++tt) {
#pragma unroll
            for (int qq = 0; qq < 4; ++qq) {
                float gi = acc[tt][qq];
                float gf = acc[4 + tt][qq];
                float gg = acc[8 + tt][qq];
                float go = acc[12 + tt][qq];
                float cn = sigm(gf) * cst[tt][qq] + sigm(gi) * tanhfast(gg);
                float hn = sigm(go) * tanhfast(cn);
                cst[tt][qq] = upd ? cn : cst[tt][qq];
                ho[tt][qq]  = upd ? hn : ho[tt][qq];
            }
        }
        // repack frozen h (f32) -> bf16 B-fragments for next step (lane-local)
#pragma unroll
        for (int i2 = 0; i2 < 8; ++i2) {
            bh0[i2] = (short)f2bf(ho[i2 >> 1][i2 & 1]);
            bh1[i2] = (short)f2bf(ho[i2 >> 1][2 + (i2 & 1)]);
        }
        cx0 = nx0; cx1 = nx1;
    }

    float* outw = out + (size_t)word * (2 * HID) + dir * HID;
#pragma unroll
    for (int tt = 0; tt < 4; ++tt) {
#pragma unroll
        for (int qq = 0; qq < 4; ++qq) {
            int j = 32 * (qq >> 1) + 8 * s + 2 * tt + (qq & 1);
            if (j < HID) outw[j] = ho[tt][qq];
        }
    }
}

// ---------------- R1 fallback (scalar f32) ----------------
__global__ __launch_bounds__(BLK, 2)
void bilstm_fallback_kernel(const int* __restrict__ chars,
                            const int* __restrict__ lengths,
                            const float* __restrict__ emb,
                            const float* __restrict__ Wih_f, const float* __restrict__ Whh_f, const float* __restrict__ b_f,
                            const float* __restrict__ Wih_b, const float* __restrict__ Whh_b, const float* __restrict__ b_b,
                            const int* __restrict__ perm,
                            float* __restrict__ out, int nw, int ml)
{
    const int dir = blockIdx.y;
    const float* Wih = dir ? Wih_b : Wih_f;
    const float* Whh = dir ? Whh_b : Whh_f;
    const float* bv  = dir ? b_b  : b_f;
    __shared__ float4 sWU4[HID * 100];
    __shared__ float4 sB4[HID];
    {
        float* p = (float*)sWU4;
        for (int i = threadIdx.x; i < HID * 100 * 4; i += BLK) {
            int g = i & 3, r = i >> 2, j = r / 100, k = r - j * 100;
            p[i] = (k < EMBD) ? Wih[(j + g * HID) * EMBD + k]
                              : Whh[(j + g * HID) * HID + (k - EMBD)];
        }
        if (threadIdx.x < HID) {
            int j = threadIdx.x;
            sB4[j] = make_float4(bv[j], bv[j + HID], bv[j + 2*HID], bv[j + 3*HID]);
        }
    }
    __syncthreads();
    int gid = blockIdx.x * BLK + threadIdx.x;
    if (gid >= nw) return;
    int word = perm ? perm[gid] : gid;
    int len  = lengths[word];
    float h[HID], x[EMBD], c[HID], hn[HID];
#pragma unroll
    for (int j = 0; j < HID; ++j) h[j] = 0.f;
#pragma unroll 1
    for (int j = 0; j < HID; ++j) c[j] = 0.f;
    const int* wch = chars + word * ml;
    float* op = out + (size_t)word * (2 * HID) + dir * HID;
#pragma unroll 1
    for (int t = 0; t < len; ++t) {
        int pos = dir ? (len - 1 - t) : t;
        int ch = wch[pos];
        const float2* ep = (const float2*)(emb + ch * EMBD);
#pragma unroll
        for (int k = 0; k < EMBD / 2; ++k) { float2 v = ep[k]; x[2*k] = v.x; x[2*k+1] = v.y; }
#pragma unroll 1
        for (int j = 0; j < HID; ++j) {
            const float4* wpt = sWU4 + j * 100;
            float4 bb = sB4[j];
            float gi = bb.x, gf = bb.y, gg = bb.z, go = bb.w;
#pragma unroll
            for (int k = 0; k < EMBD; ++k) {
                float4 w = wpt[k]; float xv = x[k];
                gi += w.x*xv; gf += w.y*xv; gg += w.z*xv; go += w.w*xv;
            }
#pragma unroll
            for (int k = 0; k < HID; ++k) {
                float4 w = wpt[EMBD + k]; float hv = h[k];
                gi += w.x*hv; gf += w.y*hv; gg += w.z*hv; go += w.w*hv;
            }
            float cn = sigm(gf) * c[j] + sigm(gi) * tanhfast(gg);
            c[j] = cn;
            hn[j] = sigm(go) * tanhfast(cn);
        }
#pragma unroll
        for (int j = 0; j < HID; ++j) h[j] = hn[j];
    }
#pragma unroll
    for (int j = 0; j < HID / 2; ++j)
        ((float2*)op)[j] = make_float2(h[2*j], h[2*j+1]);
}

extern "C" void kernel_launch(void* const* d_in, const int* in_sizes, int n_in,
                              void* d_out, int out_size, void* d_ws, size_t ws_size,
                              hipStream_t stream) {
    const int*   chars = (const int*)  d_in[0];
    const int*   lens  = (const int*)  d_in[1];
    const float* emb   = (const float*)d_in[2];
    const float* Wih_f = (const float*)d_in[3];
    const float* Whh_f = (const float*)d_in[4];
    const float* b_f   = (const float*)d_in[5];
    const float* Wih_b = (const float*)d_in[6];
    const float* Whh_b = (const float*)d_in[7];
    const float* b_b   = (const float*)d_in[8];
    float* out = (float*)d_out;

    const int nw    = in_sizes[1];
    const int ml    = in_sizes[0] / nw;
    const int vocab = in_sizes[2] / EMBD;

    size_t sortNeed = (size_t)(100 + nw) * 4;
    size_t embOff   = (sortNeed + 255) & ~(size_t)255;
    size_t embBytes = (size_t)vocab * 64 * 2;
    size_t wOff     = (embOff + embBytes + 1023) & ~(size_t)1023;
    size_t need     = wOff + 131072;

    int* ws = (int*)d_ws;
    bool haveSort = ws_size >= sortNeed;
    if (haveSort) {
        zero_counts_kernel<<<1, 128, 0, stream>>>(ws);
        hist_kernel<<<(nw + 255) / 256, 256, 0, stream>>>(lens, ws, nw);
        prefix_kernel<<<1, 1, 0, stream>>>(ws);
        scatter_kernel<<<(nw + 255) / 256, 256, 0, stream>>>(lens, ws, nw);
    }

    if (ws_size >= need && haveSort) {
        unsigned short* embp = (unsigned short*)((char*)d_ws + embOff);
        unsigned short* wpk  = (unsigned short*)((char*)d_ws + wOff);
        pack_emb_kernel<<<(vocab * 64 + 255) / 256, 256, 0, stream>>>(emb, embp, vocab);
        pack_w_kernel<<<256, 256, 0, stream>>>(Wih_f, Whh_f, b_f, Wih_b, Whh_b, b_b, wpk);
        dim3 grid((nw + 63) / 64, 2);
        bilstm_mfma_kernel<<<grid, BLK, 0, stream>>>(chars, lens, ws + 100, embp, wpk,
                                                     out, nw, ml);
    } else {
        dim3 grid((nw + BLK - 1) / BLK, 2);
        bilstm_fallback_kernel<<<grid, BLK, 0, stream>>>(chars, lens, emb,
                                                         Wih_f, Whh_f, b_f,
                                                         Wih_b, Whh_b, b_b,
                                                         haveSort ? ws + 100 : nullptr,
                                                         out, nw, ml);
    }
}

// Round 7
// 1464.446 us; speedup vs baseline: 2.3164x; 1.1981x over previous
//
#include <hip/hip_runtime.h>

#define EMBD 50
#define HID 50
#define BLK 256

typedef float f32x4 __attribute__((ext_vector_type(4)));
typedef short short8 __attribute__((ext_vector_type(8)));

__device__ __forceinline__ int imax(int a, int b) { return a > b ? a : b; }
__device__ __forceinline__ int imin(int a, int b) { return a < b ? a : b; }

__device__ __forceinline__ unsigned short f2bf(float f) {
    unsigned u = __float_as_uint(f);
    u += 0x7FFFu + ((u >> 16) & 1u);
    return (unsigned short)(u >> 16);
}
__device__ __forceinline__ float sigm(float x) {
    return __fdividef(1.0f, 1.0f + __expf(-x));
}
__device__ __forceinline__ float tanhfast(float x) {
    float e = __expf(2.0f * x);
    return 1.0f - __fdividef(2.0f, e + 1.0f);
}

// ---------------- length bucket sort ----------------
// ws ints: [0,25) counts, [25,50) bases, [50,75) cursors, [100,100+NW) perm
__global__ void zero_counts_kernel(int* ws) {
    if (threadIdx.x < 75) ws[threadIdx.x] = 0;
}
__global__ void hist_kernel(const int* __restrict__ lengths, int* ws, int nw) {
    int i = blockIdx.x * blockDim.x + threadIdx.x;
    if (i < nw) atomicAdd(&ws[lengths[i]], 1);
}
__global__ void prefix_kernel(int* ws) {
    if (threadIdx.x == 0 && blockIdx.x == 0) {
        int acc = 0;
        for (int l = 0; l <= 24; ++l) { ws[25 + l] = acc; acc += ws[l]; }
    }
}
__global__ void scatter_kernel(const int* __restrict__ lengths, int* ws, int nw) {
    int i = blockIdx.x * blockDim.x + threadIdx.x;
    if (i < nw) {
        int l = lengths[i];
        int pos = ws[25 + l] + atomicAdd(&ws[50 + l], 1);
        ws[100 + pos] = i;
    }
}

// ---------------- packing kernels ----------------
__global__ void pack_emb_kernel(const float* __restrict__ emb, unsigned short* __restrict__ embp,
                                int vocab) {
    int i = blockIdx.x * blockDim.x + threadIdx.x;
    if (i >= vocab * 64) return;
    int v = i >> 6, e = i & 63;
    float val = (e < EMBD) ? emb[v * EMBD + e] : (e == 63 ? 1.0f : 0.0f);
    embp[i] = f2bf(val);
}

// Weight A-fragments, row-permuted so feedback is lane-local (see R2 notes).
__global__ void pack_w_kernel(const float* __restrict__ Wih_f, const float* __restrict__ Whh_f,
                              const float* __restrict__ b_f,
                              const float* __restrict__ Wih_b, const float* __restrict__ Whh_b,
                              const float* __restrict__ b_b,
                              unsigned short* __restrict__ wp) {
    int tid = blockIdx.x * blockDim.x + threadIdx.x;
    if (tid >= 65536) return;
    int i    = tid & 7;
    int lane = (tid >> 3) & 63;
    int kc   = (tid >> 9) & 3;
    int gt   = (tid >> 11) & 15;
    int dir  = (tid >> 15) & 1;
    const float* Wih = dir ? Wih_b : Wih_f;
    const float* Whh = dir ? Whh_b : Whh_f;
    const float* bv  = dir ? b_b   : b_f;

    int m = lane & 15, grp = lane >> 4;
    int P = gt * 16 + m;
    int b = P >> 6, pp = P & 63;
    int tt = pp >> 4, ss = (pp >> 2) & 3, qq = pp & 3;
    int j = 32 * (qq >> 1) + 8 * ss + 2 * tt + (qq & 1);
    int kk = kc * 32 + 8 * grp + i;

    float val = 0.0f;
    if (j < HID) {
        int row = b * HID + j;
        if (kk < 64) {
            if (kk < EMBD)      val = Wih[row * EMBD + kk];
            else if (kk == 63)  val = bv[row];
        } else {
            int hk = kk - 64;
            if (hk < HID)       val = Whh[row * HID + hk];
        }
    }
    wp[tid] = f2bf(val);
}

// ---------------- main MFMA kernel ----------------
// By-value MFMA helper: no address-taking of the accumulator (keeps acc in VGPRs).
__device__ __forceinline__ f32x4 mf(const unsigned short* sWl, int gt, int kc,
                                    short8 bb, f32x4 acc) {
    const short8 aw = *(const short8*)(sWl + (gt * 4 + kc) * 512);
    return __builtin_amdgcn_mfma_f32_16x16x32_bf16(aw, bb, acc, 0, 0, 0);
}

#define MSTEP(KC, BB) \
    a0  = mf(sWl, 0,  KC, BB, a0);  a1  = mf(sWl, 1,  KC, BB, a1);  \
    a2  = mf(sWl, 2,  KC, BB, a2);  a3  = mf(sWl, 3,  KC, BB, a3);  \
    a4  = mf(sWl, 4,  KC, BB, a4);  a5  = mf(sWl, 5,  KC, BB, a5);  \
    a6  = mf(sWl, 6,  KC, BB, a6);  a7  = mf(sWl, 7,  KC, BB, a7);  \
    a8  = mf(sWl, 8,  KC, BB, a8);  a9  = mf(sWl, 9,  KC, BB, a9);  \
    a10 = mf(sWl, 10, KC, BB, a10); a11 = mf(sWl, 11, KC, BB, a11); \
    a12 = mf(sWl, 12, KC, BB, a12); a13 = mf(sWl, 13, KC, BB, a13); \
    a14 = mf(sWl, 14, KC, BB, a14); a15 = mf(sWl, 15, KC, BB, a15);

#define GATE4(AI, AF, AG, AO, T)                                        \
    _Pragma("unroll")                                                   \
    for (int qq = 0; qq < 4; ++qq) {                                    \
        float gi = (AI)[qq], gf = (AF)[qq], gg = (AG)[qq], go = (AO)[qq]; \
        float cn = sigm(gf) * cst[T][qq] + sigm(gi) * tanhfast(gg);     \
        float hn = sigm(go) * tanhfast(cn);                             \
        cst[T][qq] = upd ? cn : cst[T][qq];                             \
        ho[T][qq]  = upd ? hn : ho[T][qq];                              \
    }

__global__ __launch_bounds__(BLK, 2)
void bilstm_mfma_kernel(const int* __restrict__ chars,
                        const int* __restrict__ lengths,
                        const int* __restrict__ perm,
                        const unsigned short* __restrict__ embp,
                        const unsigned short* __restrict__ wp,
                        float* __restrict__ out, int nw, int ml)
{
    const int dir = blockIdx.y;
    __shared__ unsigned short sW[32768];   // 64 KB of A-fragments for this dir
    {
        const float4* src = (const float4*)(wp + dir * 32768);
        float4* dst = (float4*)sW;
        for (int i = threadIdx.x; i < 4096; i += BLK) dst[i] = src[i];
    }
    __syncthreads();

    const int lane = threadIdx.x & 63;
    const int wv   = threadIdx.x >> 6;
    const int wcol = lane & 15;          // word column
    const int s    = lane >> 4;          // lane group

    int gidx = (blockIdx.x * 4 + wv) * 16 + wcol;
    gidx = imin(gidx, nw - 1);
    const int word = perm[gidx];
    const int len  = lengths[word];

    int lmax = len;
    lmax = imax(lmax, __shfl_xor(lmax, 1));
    lmax = imax(lmax, __shfl_xor(lmax, 2));
    lmax = imax(lmax, __shfl_xor(lmax, 4));
    lmax = imax(lmax, __shfl_xor(lmax, 8));

    const int* charp = chars + (size_t)word * ml;
    const unsigned short* sWl = sW + lane * 8;

    float cst[4][4], ho[4][4];
#pragma unroll
    for (int a = 0; a < 4; ++a)
#pragma unroll
        for (int b = 0; b < 4; ++b) { cst[a][b] = 0.0f; ho[a][b] = 0.0f; }
    short8 bh0, bh1;
#pragma unroll
    for (int i2 = 0; i2 < 8; ++i2) { bh0[i2] = 0; bh1[i2] = 0; }

    // prefetch x for t=0
    short8 cx0, cx1;
    if (lmax > 0) {
        int pos0 = dir ? imax(len - 1, 0) : 0;
        int ch = charp[pos0];
        cx0 = *(const short8*)(embp + ch * 64 + 8 * s);
        cx1 = *(const short8*)(embp + ch * 64 + 32 + 8 * s);
    }

    for (int t = 0; t < lmax; ++t) {
        const f32x4 zz = {0.0f, 0.0f, 0.0f, 0.0f};
        f32x4 a0 = zz, a1 = zz, a2 = zz, a3 = zz,
              a4 = zz, a5 = zz, a6 = zz, a7 = zz,
              a8 = zz, a9 = zz, a10 = zz, a11 = zz,
              a12 = zz, a13 = zz, a14 = zz, a15 = zz;

        MSTEP(0, cx0)
        MSTEP(1, cx1)
        MSTEP(2, bh0)
        MSTEP(3, bh1)

        // prefetch next step's x while MFMAs retire
        int tn = (t + 1 < lmax) ? t + 1 : t;
        int posn = dir ? imax(len - 1 - tn, 0) : tn;
        int chn = charp[posn];
        short8 nx0 = *(const short8*)(embp + chn * 64 + 8 * s);
        short8 nx1 = *(const short8*)(embp + chn * 64 + 32 + 8 * s);

        const bool upd = (t < len);
        GATE4(a0, a4, a8,  a12, 0)
        GATE4(a1, a5, a9,  a13, 1)
        GATE4(a2, a6, a10, a14, 2)
        GATE4(a3, a7, a11, a15, 3)

        // repack frozen h (f32) -> bf16 B-fragments for next step (lane-local)
#pragma unroll
        for (int i2 = 0; i2 < 8; ++i2) {
            bh0[i2] = (short)f2bf(ho[i2 >> 1][i2 & 1]);
            bh1[i2] = (short)f2bf(ho[i2 >> 1][2 + (i2 & 1)]);
        }
        cx0 = nx0; cx1 = nx1;
    }

    float* outw = out + (size_t)word * (2 * HID) + dir * HID;
#pragma unroll
    for (int tt = 0; tt < 4; ++tt) {
#pragma unroll
        for (int qq = 0; qq < 4; ++qq) {
            int j = 32 * (qq >> 1) + 8 * s + 2 * tt + (qq & 1);
            if (j < HID) outw[j] = ho[tt][qq];
        }
    }
}

// ---------------- R1 fallback (scalar f32) ----------------
__global__ __launch_bounds__(BLK, 2)
void bilstm_fallback_kernel(const int* __restrict__ chars,
                            const int* __restrict__ lengths,
                            const float* __restrict__ emb,
                            const float* __restrict__ Wih_f, const float* __restrict__ Whh_f, const float* __restrict__ b_f,
                            const float* __restrict__ Wih_b, const float* __restrict__ Whh_b, const float* __restrict__ b_b,
                            const int* __restrict__ perm,
                            float* __restrict__ out, int nw, int ml)
{
    const int dir = blockIdx.y;
    const float* Wih = dir ? Wih_b : Wih_f;
    const float* Whh = dir ? Whh_b : Whh_f;
    const float* bv  = dir ? b_b  : b_f;
    __shared__ float4 sWU4[HID * 100];
    __shared__ float4 sB4[HID];
    {
        float* p = (float*)sWU4;
        for (int i = threadIdx.x; i < HID * 100 * 4; i += BLK) {
            int g = i & 3, r = i >> 2, j = r / 100, k = r - j * 100;
            p[i] = (k < EMBD) ? Wih[(j + g * HID) * EMBD + k]
                              : Whh[(j + g * HID) * HID + (k - EMBD)];
        }
        if (threadIdx.x < HID) {
            int j = threadIdx.x;
            sB4[j] = make_float4(bv[j], bv[j + HID], bv[j + 2*HID], bv[j + 3*HID]);
        }
    }
    __syncthreads();
    int gid = blockIdx.x * BLK + threadIdx.x;
    if (gid >= nw) return;
    int word = perm ? perm[gid] : gid;
    int len  = lengths[word];
    float h[HID], x[EMBD], c[HID], hn[HID];
#pragma unroll
    for (int j = 0; j < HID; ++j) h[j] = 0.f;
#pragma unroll 1
    for (int j = 0; j < HID; ++j) c[j] = 0.f;
    const int* wch = chars + word * ml;
    float* op = out + (size_t)word * (2 * HID) + dir * HID;
#pragma unroll 1
    for (int t = 0; t < len; ++t) {
        int pos = dir ? (len - 1 - t) : t;
        int ch = wch[pos];
        const float2* ep = (const float2*)(emb + ch * EMBD);
#pragma unroll
        for (int k = 0; k < EMBD / 2; ++k) { float2 v = ep[k]; x[2*k] = v.x; x[2*k+1] = v.y; }
#pragma unroll 1
        for (int j = 0; j < HID; ++j) {
            const float4* wpt = sWU4 + j * 100;
            float4 bb = sB4[j];
            float gi = bb.x, gf = bb.y, gg = bb.z, go = bb.w;
#pragma unroll
            for (int k = 0; k < EMBD; ++k) {
                float4 w = wpt[k]; float xv = x[k];
                gi += w.x*xv; gf += w.y*xv; gg += w.z*xv; go += w.w*xv;
            }
#pragma unroll
            for (int k = 0; k < HID; ++k) {
                float4 w = wpt[EMBD + k]; float hv = h[k];
                gi += w.x*hv; gf += w.y*hv; gg += w.z*hv; go += w.w*hv;
            }
            float cn = sigm(gf) * c[j] + sigm(gi) * tanhfast(gg);
            c[j] = cn;
            hn[j] = sigm(go) * tanhfast(cn);
        }
#pragma unroll
        for (int j = 0; j < HID; ++j) h[j] = hn[j];
    }
#pragma unroll
    for (int j = 0; j < HID / 2; ++j)
        ((float2*)op)[j] = make_float2(h[2*j], h[2*j+1]);
}

extern "C" void kernel_launch(void* const* d_in, const int* in_sizes, int n_in,
                              void* d_out, int out_size, void* d_ws, size_t ws_size,
                              hipStream_t stream) {
    const int*   chars = (const int*)  d_in[0];
    const int*   lens  = (const int*)  d_in[1];
    const float* emb   = (const float*)d_in[2];
    const float* Wih_f = (const float*)d_in[3];
    const float* Whh_f = (const float*)d_in[4];
    const float* b_f   = (const float*)d_in[5];
    const float* Wih_b = (const float*)d_in[6];
    const float* Whh_b = (const float*)d_in[7];
    const float* b_b   = (const float*)d_in[8];
    float* out = (float*)d_out;

    const int nw    = in_sizes[1];
    const int ml    = in_sizes[0] / nw;
    const int vocab = in_sizes[2] / EMBD;

    size_t sortNeed = (size_t)(100 + nw) * 4;
    size_t embOff   = (sortNeed + 255) & ~(size_t)255;
    size_t embBytes = (size_t)vocab * 64 * 2;
    size_t wOff     = (embOff + embBytes + 1023) & ~(size_t)1023;
    size_t need     = wOff + 131072;

    int* ws = (int*)d_ws;
    bool haveSort = ws_size >= sortNeed;
    if (haveSort) {
        zero_counts_kernel<<<1, 128, 0, stream>>>(ws);
        hist_kernel<<<(nw + 255) / 256, 256, 0, stream>>>(lens, ws, nw);
        prefix_kernel<<<1, 1, 0, stream>>>(ws);
        scatter_kernel<<<(nw + 255) / 256, 256, 0, stream>>>(lens, ws, nw);
    }

    if (ws_size >= need && haveSort) {
        unsigned short* embp = (unsigned short*)((char*)d_ws + embOff);
        unsigned short* wpk  = (unsigned short*)((char*)d_ws + wOff);
        pack_emb_kernel<<<(vocab * 64 + 255) / 256, 256, 0, stream>>>(emb, embp, vocab);
        pack_w_kernel<<<256, 256, 0, stream>>>(Wih_f, Whh_f, b_f, Wih_b, Whh_b, b_b, wpk);
        dim3 grid((nw + 63) / 64, 2);
        bilstm_mfma_kernel<<<grid, BLK, 0, stream>>>(chars, lens, ws + 100, embp, wpk,
                                                     out, nw, ml);
    } else {
        dim3 grid((nw + BLK - 1) / BLK, 2);
        bilstm_fallback_kernel<<<grid, BLK, 0, stream>>>(chars, lens, emb,
                                                         Wih_f, Whh_f, b_f,
                                                         Whh_b == nullptr ? b_b : Wih_b, Whh_b, b_b,
                                                         haveSort ? ws + 100 : nullptr,
                                                         out, nw, ml);
    }
}